// Round 1
// baseline (258.373 us; speedup 1.0000x reference)
//
#include <hip/hip_runtime.h>
#include <hip/hip_bf16.h>
#include <math.h>

#define N_NODES 50000
#define N_EDGES 800000
#define F 64
#define CUTOFF2 100.0f

__device__ __forceinline__ float silu_f(float v) {
    return v / (1.0f + __expf(-v));
}

// broadcast lane k's value of v to all lanes (v_readlane -> SGPR)
__device__ __forceinline__ float bcast_lane(float v, int k) {
    return __int_as_float(__builtin_amdgcn_readlane(__float_as_int(v), k));
}

// Kernel 1: per-node linear parts.
//   out[n] = x[n] @ Wp + bp          (base of final output)
//   h1[n]  = x[n] @ W1[:64] + b1     (hoisted edge-MLP feature part)
// One wave per node; lane c owns column c; W columns live in VGPRs.
__global__ __launch_bounds__(256) void node_kernel(
    const float* __restrict__ x, const float* __restrict__ Wp,
    const float* __restrict__ bp, const float* __restrict__ W1,
    const float* __restrict__ b1, float* __restrict__ out,
    float* __restrict__ h1)
{
    const int lane   = threadIdx.x & 63;
    const int wid    = blockIdx.x * (blockDim.x >> 6) + (threadIdx.x >> 6);
    const int nwaves = gridDim.x * (blockDim.x >> 6);

    float wp[F], w1a[F];
    #pragma unroll
    for (int k = 0; k < F; ++k) {
        wp[k]  = Wp[k * F + lane];
        w1a[k] = W1[k * F + lane];
    }
    const float bpc = bp[lane];
    const float b1c = b1[lane];

    for (int n = wid; n < N_NODES; n += nwaves) {
        const float xv = x[(size_t)n * F + lane];   // lane c holds x[n][c]
        float accp = bpc, acc1 = b1c;
        #pragma unroll
        for (int k = 0; k < F; ++k) {
            const float xk = bcast_lane(xv, k);
            accp = fmaf(xk, wp[k],  accp);
            acc1 = fmaf(xk, w1a[k], acc1);
        }
        out[(size_t)n * F + lane] = accp;
        h1 [(size_t)n * F + lane] = acc1;
    }
}

// Kernel 2: per-edge cutoff test + radial MLP + stream compaction.
// Thread per edge. Active edges (d < 10) append a 32B record:
//   {src, tgt, radial[4], cutoff, pad}
__global__ __launch_bounds__(256) void edge_prep_kernel(
    const int* __restrict__ ei, const float* __restrict__ pos,
    const float* __restrict__ Wr1, const float* __restrict__ br1,
    const float* __restrict__ Wr2, const float* __restrict__ br2,
    float* __restrict__ recs, int* __restrict__ counter)
{
    const int e    = blockIdx.x * blockDim.x + threadIdx.x;
    const int lane = threadIdx.x & 63;

    bool  active = false;
    float r0 = 0.f, r1 = 0.f, r2 = 0.f, r3 = 0.f, cut = 0.f;
    int   src = 0, tgt = 0;

    if (e < N_EDGES) {
        src = ei[e];
        tgt = ei[N_EDGES + e];
        const float dx = pos[3 * tgt + 0] - pos[3 * src + 0];
        const float dy = pos[3 * tgt + 1] - pos[3 * src + 1];
        const float dz = pos[3 * tgt + 2] - pos[3 * src + 2];
        const float d2 = dx * dx + dy * dy + dz * dz;
        if (d2 < CUTOFF2) {
            active = true;
            const float d = sqrtf(d2);
            float a0 = br2[0], a1 = br2[1], a2 = br2[2], a3 = br2[3];
            #pragma unroll
            for (int i = 0; i < 16; ++i) {
                const float t = silu_f(fmaf(d, Wr1[i], br1[i]));
                a0 = fmaf(t, Wr2[i * 4 + 0], a0);
                a1 = fmaf(t, Wr2[i * 4 + 1], a1);
                a2 = fmaf(t, Wr2[i * 4 + 2], a2);
                a3 = fmaf(t, Wr2[i * 4 + 3], a3);
            }
            r0 = silu_f(a0); r1 = silu_f(a1);
            r2 = silu_f(a2); r3 = silu_f(a3);
            cut = 1.0f - d2 * 0.01f;   // in (0,1] when d2 < 100; no clip needed
        }
    }

    const unsigned long long m = __ballot(active);
    const int cnt = __popcll(m);
    int base = 0;
    if (lane == 0 && cnt) base = atomicAdd(counter, cnt);
    base = __shfl(base, 0);
    if (active) {
        const int idx = base + __popcll(m & ((1ull << lane) - 1ull));
        float4* p = (float4*)(recs + (size_t)idx * 8);
        p[0] = make_float4(__int_as_float(src), __int_as_float(tgt), r0, r1);
        p[1] = make_float4(r2, r3, cut, 0.0f);
    }
}

// Kernel 3: main edge MLP on compacted edges + scatter-add.
// One wave per active edge; lane c owns output column c.
//   hidden = silu(h1[src] + radial @ W1[64:68])
//   ef     = silu(hidden @ W2 + b2) * cutoff
//   out[tgt] += ef   (coalesced 256B hardware f32 atomics)
__global__ __launch_bounds__(256) void edge_main_kernel(
    const float* __restrict__ recs, const int* __restrict__ counter,
    const float* __restrict__ h1, const float* __restrict__ W1,
    const float* __restrict__ W2, const float* __restrict__ b2,
    float* __restrict__ out)
{
    const int lane = threadIdx.x & 63;
    const int wid  = __builtin_amdgcn_readfirstlane(
        blockIdx.x * (blockDim.x >> 6) + (threadIdx.x >> 6));
    const int nwaves = gridDim.x * (blockDim.x >> 6);

    float w2[F];
    #pragma unroll
    for (int k = 0; k < F; ++k) w2[k] = W2[k * F + lane];
    const float w1r0 = W1[(F + 0) * F + lane];
    const float w1r1 = W1[(F + 1) * F + lane];
    const float w1r2 = W1[(F + 2) * F + lane];
    const float w1r3 = W1[(F + 3) * F + lane];
    const float b2c  = b2[lane];

    const int cnt = counter[0];
    for (int e = wid; e < cnt; e += nwaves) {
        const float* r = recs + (size_t)e * 8;   // uniform -> scalar loads
        const int   src = __float_as_int(r[0]);
        const int   tgt = __float_as_int(r[1]);
        const float rr0 = r[2], rr1 = r[3], rr2 = r[4], rr3 = r[5];
        const float cut = r[6];

        float h = h1[(size_t)src * F + lane];
        h = fmaf(rr0, w1r0, h);
        h = fmaf(rr1, w1r1, h);
        h = fmaf(rr2, w1r2, h);
        h = fmaf(rr3, w1r3, h);
        h = silu_f(h);

        float ef0 = 0.f, ef1 = 0.f, ef2 = 0.f, ef3 = 0.f;
        #pragma unroll
        for (int k = 0; k < F; k += 4) {
            ef0 = fmaf(bcast_lane(h, k + 0), w2[k + 0], ef0);
            ef1 = fmaf(bcast_lane(h, k + 1), w2[k + 1], ef1);
            ef2 = fmaf(bcast_lane(h, k + 2), w2[k + 2], ef2);
            ef3 = fmaf(bcast_lane(h, k + 3), w2[k + 3], ef3);
        }
        const float v  = ((ef0 + ef1) + (ef2 + ef3)) + b2c;
        const float ef = silu_f(v) * cut;
        unsafeAtomicAdd(&out[(size_t)tgt * F + lane], ef);
    }
}

extern "C" void kernel_launch(void* const* d_in, const int* in_sizes, int n_in,
                              void* d_out, int out_size, void* d_ws, size_t ws_size,
                              hipStream_t stream) {
    const float* x   = (const float*)d_in[0];
    const int*   ei  = (const int*)d_in[1];
    const float* pos = (const float*)d_in[2];
    const float* Wp  = (const float*)d_in[3];
    const float* bp  = (const float*)d_in[4];
    const float* W1  = (const float*)d_in[5];
    const float* b1  = (const float*)d_in[6];
    const float* W2  = (const float*)d_in[7];
    const float* b2  = (const float*)d_in[8];
    const float* Wr1 = (const float*)d_in[9];
    const float* br1 = (const float*)d_in[10];
    const float* Wr2 = (const float*)d_in[11];
    const float* br2 = (const float*)d_in[12];
    float* out = (float*)d_out;

    // workspace layout: [counter 256B][h1 12.8MB][recs 25.6MB]  (~38.4MB)
    char*  ws      = (char*)d_ws;
    int*   counter = (int*)ws;
    float* h1      = (float*)(ws + 256);
    float* recs    = (float*)(ws + 256 + (size_t)N_NODES * F * sizeof(float));

    hipMemsetAsync(counter, 0, sizeof(int), stream);
    node_kernel<<<1024, 256, 0, stream>>>(x, Wp, bp, W1, b1, out, h1);
    edge_prep_kernel<<<(N_EDGES + 255) / 256, 256, 0, stream>>>(
        ei, pos, Wr1, br1, Wr2, br2, recs, counter);
    edge_main_kernel<<<2048, 256, 0, stream>>>(
        recs, counter, h1, W1, W2, b2, out);
}

// Round 2
// 127.584 us; speedup vs baseline: 2.0251x; 2.0251x over previous
//
#include <hip/hip_runtime.h>
#include <hip/hip_bf16.h>
#include <math.h>

#define N_NODES 50000
#define N_EDGES 800000
#define F 64
#define CUTOFF2 100.0f
#define P_BLOCKS 2048
#define CHUNK 391            // ceil(800000 / 2048)

__device__ __forceinline__ float silu_f(float v) {
    return v / (1.0f + __expf(-v));
}

__device__ __forceinline__ float bcast_lane(float v, int k) {
    return __int_as_float(__builtin_amdgcn_readlane(__float_as_int(v), k));
}

// Kernel 1: per-node linear parts.
//   out[n] = x[n] @ Wp + bp          (base of final output)
//   h1[n]  = x[n] @ W1[:64] + b1     (hoisted edge-MLP feature part)
__global__ __launch_bounds__(256) void node_kernel(
    const float* __restrict__ x, const float* __restrict__ Wp,
    const float* __restrict__ bp, const float* __restrict__ W1,
    const float* __restrict__ b1, float* __restrict__ out,
    float* __restrict__ h1)
{
    const int lane   = threadIdx.x & 63;
    const int wid    = blockIdx.x * (blockDim.x >> 6) + (threadIdx.x >> 6);
    const int nwaves = gridDim.x * (blockDim.x >> 6);

    float wp[F], w1a[F];
    #pragma unroll
    for (int k = 0; k < F; ++k) {
        wp[k]  = Wp[k * F + lane];
        w1a[k] = W1[k * F + lane];
    }
    const float bpc = bp[lane];
    const float b1c = b1[lane];

    for (int n = wid; n < N_NODES; n += nwaves) {
        const float xv = x[(size_t)n * F + lane];
        float accp = bpc, acc1 = b1c;
        #pragma unroll
        for (int k = 0; k < F; ++k) {
            const float xk = bcast_lane(xv, k);
            accp = fmaf(xk, wp[k],  accp);
            acc1 = fmaf(xk, w1a[k], acc1);
        }
        out[(size_t)n * F + lane] = accp;
        h1 [(size_t)n * F + lane] = acc1;
    }
}

// Kernel 2: cutoff test + radial MLP + per-block-region compaction.
// Block j owns edges [j*CHUNK, (j+1)*CHUNK) and region recs[j*CHUNK*8 ...].
// NO global atomics — block-local LDS counter only.
// Record (32B): {src, tgt, r0, r1, r2, r3, cutoff, pad}
__global__ __launch_bounds__(256) void edge_prep_kernel(
    const int* __restrict__ ei, const float* __restrict__ pos,
    const float* __restrict__ Wr1, const float* __restrict__ br1,
    const float* __restrict__ Wr2, const float* __restrict__ br2,
    float* __restrict__ recs, int* __restrict__ counts)
{
    __shared__ int s_off;
    if (threadIdx.x == 0) s_off = 0;
    __syncthreads();

    const int lane = threadIdx.x & 63;
    const int j    = blockIdx.x;
    const int e0   = j * CHUNK;
    const int e1   = min(e0 + CHUNK, N_EDGES);
    float* rbase   = recs + (size_t)j * CHUNK * 8;

    for (int base = e0; base < e1; base += 256) {
        const int e = base + threadIdx.x;
        bool  active = false;
        float r0 = 0.f, r1 = 0.f, r2 = 0.f, r3 = 0.f, cut = 0.f;
        int   src = 0, tgt = 0;

        if (e < e1) {
            src = ei[e];
            tgt = ei[N_EDGES + e];
            const float dx = pos[3 * tgt + 0] - pos[3 * src + 0];
            const float dy = pos[3 * tgt + 1] - pos[3 * src + 1];
            const float dz = pos[3 * tgt + 2] - pos[3 * src + 2];
            const float d2 = dx * dx + dy * dy + dz * dz;
            if (d2 < CUTOFF2) {
                active = true;
                const float d = sqrtf(d2);
                float a0 = br2[0], a1 = br2[1], a2 = br2[2], a3 = br2[3];
                #pragma unroll
                for (int i = 0; i < 16; ++i) {
                    const float t = silu_f(fmaf(d, Wr1[i], br1[i]));
                    a0 = fmaf(t, Wr2[i * 4 + 0], a0);
                    a1 = fmaf(t, Wr2[i * 4 + 1], a1);
                    a2 = fmaf(t, Wr2[i * 4 + 2], a2);
                    a3 = fmaf(t, Wr2[i * 4 + 3], a3);
                }
                r0 = silu_f(a0); r1 = silu_f(a1);
                r2 = silu_f(a2); r3 = silu_f(a3);
                cut = 1.0f - d2 * 0.01f;   // in [0,1] when d2 < 100
            }
        }

        const unsigned long long m = __ballot(active);
        const int cnt = __popcll(m);
        int wbase = 0;
        if (lane == 0 && cnt) wbase = atomicAdd(&s_off, cnt);   // LDS atomic
        wbase = __shfl(wbase, 0);
        if (active) {
            const int idx = wbase + __popcll(m & ((1ull << lane) - 1ull));
            float4* p = (float4*)(rbase + (size_t)idx * 8);
            p[0] = make_float4(__int_as_float(src), __int_as_float(tgt), r0, r1);
            p[1] = make_float4(r2, r3, cut, 0.0f);
        }
    }

    __syncthreads();
    if (threadIdx.x == 0) counts[j] = s_off;
}

// Kernel 3: main edge MLP on compacted regions + scatter-add.
// Block j processes region j's counts[j] records; one wave per edge.
//   hidden = silu(h1[src] + radial @ W1[64:68])
//   ef     = silu(hidden @ W2 + b2) * cutoff
//   out[tgt] += ef   (coalesced 256B hardware f32 atomics)
__global__ __launch_bounds__(256) void edge_main_kernel(
    const float* __restrict__ recs, const int* __restrict__ counts,
    const float* __restrict__ h1, const float* __restrict__ W1,
    const float* __restrict__ W2, const float* __restrict__ b2,
    float* __restrict__ out)
{
    const int lane = threadIdx.x & 63;
    const int w    = __builtin_amdgcn_readfirstlane(threadIdx.x >> 6);
    const int j    = blockIdx.x;

    float w2[F];
    #pragma unroll
    for (int k = 0; k < F; ++k) w2[k] = W2[k * F + lane];
    const float w1r0 = W1[(F + 0) * F + lane];
    const float w1r1 = W1[(F + 1) * F + lane];
    const float w1r2 = W1[(F + 2) * F + lane];
    const float w1r3 = W1[(F + 3) * F + lane];
    const float b2c  = b2[lane];

    const int cnt = counts[j];
    const float* rbase = recs + (size_t)j * CHUNK * 8;

    for (int i = w; i < cnt; i += 4) {
        const float* r = rbase + (size_t)i * 8;   // wave-uniform address
        const int   src = __float_as_int(r[0]);
        const int   tgt = __float_as_int(r[1]);
        const float rr0 = r[2], rr1 = r[3], rr2 = r[4], rr3 = r[5];
        const float cut = r[6];

        float h = h1[(size_t)src * F + lane];
        h = fmaf(rr0, w1r0, h);
        h = fmaf(rr1, w1r1, h);
        h = fmaf(rr2, w1r2, h);
        h = fmaf(rr3, w1r3, h);
        h = silu_f(h);

        float ef0 = 0.f, ef1 = 0.f, ef2 = 0.f, ef3 = 0.f;
        #pragma unroll
        for (int k = 0; k < F; k += 4) {
            ef0 = fmaf(bcast_lane(h, k + 0), w2[k + 0], ef0);
            ef1 = fmaf(bcast_lane(h, k + 1), w2[k + 1], ef1);
            ef2 = fmaf(bcast_lane(h, k + 2), w2[k + 2], ef2);
            ef3 = fmaf(bcast_lane(h, k + 3), w2[k + 3], ef3);
        }
        const float v  = ((ef0 + ef1) + (ef2 + ef3)) + b2c;
        const float ef = silu_f(v) * cut;
        unsafeAtomicAdd(&out[(size_t)tgt * F + lane], ef);
    }
}

extern "C" void kernel_launch(void* const* d_in, const int* in_sizes, int n_in,
                              void* d_out, int out_size, void* d_ws, size_t ws_size,
                              hipStream_t stream) {
    const float* x   = (const float*)d_in[0];
    const int*   ei  = (const int*)d_in[1];
    const float* pos = (const float*)d_in[2];
    const float* Wp  = (const float*)d_in[3];
    const float* bp  = (const float*)d_in[4];
    const float* W1  = (const float*)d_in[5];
    const float* b1  = (const float*)d_in[6];
    const float* W2  = (const float*)d_in[7];
    const float* b2  = (const float*)d_in[8];
    const float* Wr1 = (const float*)d_in[9];
    const float* br1 = (const float*)d_in[10];
    const float* Wr2 = (const float*)d_in[11];
    const float* br2 = (const float*)d_in[12];
    float* out = (float*)d_out;

    // workspace layout: [counts 8KB][h1 12.8MB][recs 25.6MB]
    char*  ws     = (char*)d_ws;
    int*   counts = (int*)ws;
    float* h1     = (float*)(ws + P_BLOCKS * sizeof(int));
    float* recs   = (float*)(ws + P_BLOCKS * sizeof(int)
                             + (size_t)N_NODES * F * sizeof(float));

    node_kernel<<<1024, 256, 0, stream>>>(x, Wp, bp, W1, b1, out, h1);
    edge_prep_kernel<<<P_BLOCKS, 256, 0, stream>>>(
        ei, pos, Wr1, br1, Wr2, br2, recs, counts);
    edge_main_kernel<<<P_BLOCKS, 256, 0, stream>>>(
        recs, counts, h1, W1, W2, b2, out);
}